// Round 8
// baseline (489.520 us; speedup 1.0000x reference)
//
#include <hip/hip_runtime.h>
#include <hip/hip_cooperative_groups.h>
#include <hip/hip_bf16.h>
#include <hip/hip_fp8.h>
#include <math.h>

namespace cg = cooperative_groups;

#define B_   2048
#define K_   256
#define AD_  512
#define IN_  768
#define NR_  500
#define NRP_ 512   // padded
#define NE_  100000
#define PITCH 72   // 64 + 8 pad (ushort units)
#define NBLK 512   // cooperative grid size (2 blocks/CU)

typedef __attribute__((ext_vector_type(8))) short short8;
typedef __attribute__((ext_vector_type(4))) float float4v;
typedef __attribute__((ext_vector_type(4))) float f32x4;

__device__ __forceinline__ unsigned short f2bf(float f) {
    unsigned int u = __float_as_uint(f);
    unsigned int r = u + 0x7FFF + ((u >> 16) & 1);   // round-to-nearest-even
    return (unsigned short)(r >> 16);
}
__device__ __forceinline__ unsigned char f2fp8(float f) {
    __hip_fp8_e4m3 t(f);                             // OCP e4m3, HW cvt on gfx950
    return (unsigned char)t.__x;
}
__device__ __forceinline__ float fp8tof(unsigned int byte) {
    __hip_fp8_e4m3 t; t.__x = (__hip_fp8_storage_t)byte; return (float)t;
}

// ---------------- prep: one quad t of {Xb | W1b | W2b | emb_rb} ---------------
#define X_N4  (B_ * IN_ / 4)     // 393,216
#define W1_N4 (AD_ * IN_ / 4)    // 98,304
#define W2_N4 (AD_ * AD_ / 4)    // 65,536
#define ER_N4 (NR_ * 256 / 4)    // 32,000
#define PREPS_TOTAL (X_N4 + W1_N4 + W2_N4 + ER_N4)   // 589,056
__device__ __forceinline__ void prep_one(
    int t, const float* __restrict__ E, const float* __restrict__ H,
    const float* __restrict__ Q, const float* __restrict__ W1,
    const float* __restrict__ W2, const float* __restrict__ emb_r,
    ushort* __restrict__ Xb, ushort* __restrict__ W1b,
    ushort* __restrict__ W2b, ushort* __restrict__ emb_rb)
{
    const float* src; ushort* dst; long off;
    if (t < X_N4) {
        const int base = t * 4;
        const int row = base / IN_, col = base % IN_;
        src = (col < 256) ? &E[row * 256 + col]
            : (col < 512) ? &H[row * 256 + col - 256]
                          : &Q[row * 256 + col - 512];
        const float4 v = *(const float4*)src;
        ushort4 o;
        o.x = f2bf(v.x); o.y = f2bf(v.y); o.z = f2bf(v.z); o.w = f2bf(v.w);
        *(ushort4*)&Xb[base] = o;
        return;
    }
    t -= X_N4;
    if (t < W1_N4)                 { src = W1;    dst = W1b;    off = t; }
    else if (t < W1_N4 + W2_N4)    { src = W2;    dst = W2b;    off = t - W1_N4; }
    else                           { src = emb_r; dst = emb_rb; off = t - W1_N4 - W2_N4; }
    const float4 v = *(const float4*)&src[off * 4];
    ushort4 o;
    o.x = f2bf(v.x); o.y = f2bf(v.y); o.z = f2bf(v.z); o.w = f2bf(v.w);
    *(ushort4*)&dst[off * 4] = o;
}

// ---------------- emb_e -> fp8 conversion slab (r1-exact, 256 blocks) ---------
#define EE_N4 (NE_ * 256 / 4)    // 6,400,000
__device__ __forceinline__ void conv_range(
    const float* __restrict__ emb_e, unsigned char* __restrict__ emb_e8,
    int q0, int q1, int cb)
{
    const int stride = 256 * 256;                 // 65,536 conversion threads
    const f32x4* __restrict__ src = (const f32x4*)emb_e;
    uchar4* __restrict__ dst = (uchar4*)emb_e8;
    int i = q0 + cb * 256 + (int)threadIdx.x;
    for (; i + 3 * stride < q1; i += 4 * stride) {
        f32x4 v0 = __builtin_nontemporal_load(src + i);
        f32x4 v1 = __builtin_nontemporal_load(src + i + stride);
        f32x4 v2 = __builtin_nontemporal_load(src + i + 2 * stride);
        f32x4 v3 = __builtin_nontemporal_load(src + i + 3 * stride);
        uchar4 o0, o1, o2, o3;
        o0.x = f2fp8(v0[0]); o0.y = f2fp8(v0[1]); o0.z = f2fp8(v0[2]); o0.w = f2fp8(v0[3]);
        o1.x = f2fp8(v1[0]); o1.y = f2fp8(v1[1]); o1.z = f2fp8(v1[2]); o1.w = f2fp8(v1[3]);
        o2.x = f2fp8(v2[0]); o2.y = f2fp8(v2[1]); o2.z = f2fp8(v2[2]); o2.w = f2fp8(v2[3]);
        o3.x = f2fp8(v3[0]); o3.y = f2fp8(v3[1]); o3.z = f2fp8(v3[2]); o3.w = f2fp8(v3[3]);
        dst[i] = o0; dst[i + stride] = o1; dst[i + 2 * stride] = o2; dst[i + 3 * stride] = o3;
    }
    for (; i < q1; i += stride) {
        f32x4 v = __builtin_nontemporal_load(src + i);
        uchar4 o;
        o.x = f2fp8(v[0]); o.y = f2fp8(v[1]); o.z = f2fp8(v[2]); o.w = f2fp8(v[3]);
        dst[i] = o;
    }
}

// ---------------- bf16 MFMA 64x64 GEMM tile, BK=64, dbuf LDS (r1-exact) -------
template<int K, bool RELU, bool OUT_BF16, bool BIAS, bool EMIT_RHALF>
__device__ __forceinline__ void gemm_tile(
    const ushort* __restrict__ A, const ushort* __restrict__ Bw,
    const float* __restrict__ bias, ushort* __restrict__ outb,
    float* __restrict__ outf, ushort* __restrict__ rhalf,
    const int n0, const int m0, ushort* __restrict__ Asl, ushort* __restrict__ Bsl)
{
    const int tid = threadIdx.x;
    const int lane = tid & 63, w = tid >> 6;
    const int lrow = tid >> 2, lcg = (tid & 3) * 16;  // 4 loaders/row x 32B
    const int q = lane >> 4, l16 = lane & 15;

    const ushort* aptr = &A[(size_t)(m0 + lrow) * K + lcg];
    const ushort* bptr = &Bw[(size_t)(n0 + lrow) * K + lcg];

    short8 ra0 = *(const short8*)aptr;
    short8 ra1 = *(const short8*)(aptr + 8);
    short8 rb0 = *(const short8*)bptr;
    short8 rb1 = *(const short8*)(bptr + 8);
    *(short8*)&Asl[lrow * PITCH + lcg]     = ra0;
    *(short8*)&Asl[lrow * PITCH + lcg + 8] = ra1;
    *(short8*)&Bsl[lrow * PITCH + lcg]     = rb0;
    *(short8*)&Bsl[lrow * PITCH + lcg + 8] = rb1;

    float4v acc[4] = {};
    int buf = 0;
    __syncthreads();
    for (int k0 = 0; k0 < K; k0 += 64) {
        if (k0 + 64 < K) {                        // prefetch next tile into regs
            ra0 = *(const short8*)(aptr + k0 + 64);
            ra1 = *(const short8*)(aptr + k0 + 64 + 8);
            rb0 = *(const short8*)(bptr + k0 + 64);
            rb1 = *(const short8*)(bptr + k0 + 64 + 8);
        }
        #pragma unroll
        for (int kh = 0; kh < 64; kh += 32) {
            const short8 af = *(const short8*)&Asl[buf * 64 * PITCH + (w * 16 + l16) * PITCH + kh + q * 8];
            #pragma unroll
            for (int jn = 0; jn < 4; ++jn) {
                const short8 bfr = *(const short8*)&Bsl[buf * 64 * PITCH + (jn * 16 + l16) * PITCH + kh + q * 8];
                acc[jn] = __builtin_amdgcn_mfma_f32_16x16x32_bf16(af, bfr, acc[jn], 0, 0, 0);
            }
        }
        if (k0 + 64 < K) {
            const int nb = (buf ^ 1) * 64 * PITCH;
            *(short8*)&Asl[nb + lrow * PITCH + lcg]     = ra0;
            *(short8*)&Asl[nb + lrow * PITCH + lcg + 8] = ra1;
            *(short8*)&Bsl[nb + lrow * PITCH + lcg]     = rb0;
            *(short8*)&Bsl[nb + lrow * PITCH + lcg + 8] = rb1;
            __syncthreads();
            buf ^= 1;
        }
    }
    #pragma unroll
    for (int jn = 0; jn < 4; ++jn) {
        const int n = n0 + jn * 16 + l16;
        const float bn = BIAS ? bias[n] : 0.0f;
        #pragma unroll
        for (int r = 0; r < 4; ++r) {
            const int m = m0 + w * 16 + q * 4 + r;
            float c = acc[jn][r] + bn;
            if (RELU) c = fmaxf(c, 0.0f);
            if (OUT_BF16) outb[(size_t)m * AD_ + n] = f2bf(c);
            else if (!EMIT_RHALF || n >= 256) outf[(size_t)m * AD_ + n] = c;
            if (EMIT_RHALF && n < 256) rhalf[(size_t)m * 256 + n] = f2bf(c);
        }
    }
}

// ---------------- scores row (r7-exact): gather-dot + masked softmax ----------
__device__ __forceinline__ void scores_row(
    const int b, const float* __restrict__ X2, const float* __restrict__ R,
    const unsigned char* __restrict__ emb_e8, const float* __restrict__ mask,
    const int* __restrict__ r_space, const int* __restrict__ e_space,
    float* __restrict__ dist, float* __restrict__ entropy,
    int* __restrict__ s_e, float* __restrict__ s_x,
    float* __restrict__ s_dot, float* __restrict__ s_red)
{
    const int tid = threadIdx.x;
    const int lane = tid & 63, wid = tid >> 6;
    const int l16 = lane & 15, q4 = lane >> 4;

    {
        const int   e_mine = e_space[b * K_ + tid];
        const float mk     = mask[b * K_ + tid];
        s_e[tid] = (mk != 0.0f) ? e_mine : 0;    // dead gathers -> row 0 (L1-hot)
        s_x[(tid >> 4) * 20 + (tid & 15)] = X2[(size_t)b * AD_ + 256 + tid];
    }
    __syncthreads();

    const int kbase = wid * 64;
    #pragma unroll
    for (int it = 0; it < 2; ++it) {
        uint4 wv[8];
        #pragma unroll
        for (int u = 0; u < 8; ++u) {
            const int row = kbase + it * 32 + u * 4 + q4;
            wv[u] = *(const uint4*)&emb_e8[(size_t)s_e[row] * 256 + l16 * 16];
        }
        float p[8];
        #pragma unroll
        for (int u = 0; u < 8; ++u) {
            float a = 0.0f;
            #pragma unroll
            for (int w4 = 0; w4 < 4; ++w4) {
                const unsigned int d = (w4 == 0) ? wv[u].x : (w4 == 1) ? wv[u].y
                                     : (w4 == 2) ? wv[u].z : wv[u].w;
                const float4 xv = *(const float4*)&s_x[l16 * 20 + w4 * 4];
                a += fp8tof(d & 0xffu)         * xv.x + fp8tof((d >> 8) & 0xffu)  * xv.y
                   + fp8tof((d >> 16) & 0xffu) * xv.z + fp8tof(d >> 24)           * xv.w;
            }
            p[u] = a;
        }
        #pragma unroll
        for (int off = 8; off >= 1; off >>= 1) {
            #pragma unroll
            for (int u = 0; u < 8; ++u) p[u] += __shfl_down(p[u], off, 16);
        }
        if (l16 == 0) {
            #pragma unroll
            for (int u = 0; u < 8; ++u) s_dot[kbase + it * 32 + u * 4 + q4] = p[u];
        }
    }
    __syncthreads();

    const float mk2    = mask[b * K_ + tid];
    const int   r_mine = r_space[b * K_ + tid];
    const float bias   = R[(size_t)b * NRP_ + r_mine] - (1.0f - mk2) * 1e31f;
    const float v = s_dot[tid] + bias;

    float m = v;
    #pragma unroll
    for (int off = 32; off >= 1; off >>= 1) m = fmaxf(m, __shfl_down(m, off));
    if (lane == 0) s_red[wid] = m;
    __syncthreads();
    if (tid == 0)
        s_red[8] = fmaxf(fmaxf(s_red[0], s_red[1]), fmaxf(s_red[2], s_red[3]));
    __syncthreads();
    const float bmax = s_red[8];

    const float ev = __expf(v - bmax);       // masked: exp(-1e31)=0
    float s = ev;
    float t = ev * (v - bmax);               // masked: 0 * finite = 0
    #pragma unroll
    for (int off = 32; off >= 1; off >>= 1) {
        s += __shfl_down(s, off);
        t += __shfl_down(t, off);
    }
    if (lane == 0) { s_red[wid] = s; s_red[4 + wid] = t; }
    __syncthreads();
    if (tid == 0) {
        s_red[9]  = s_red[0] + s_red[1] + s_red[2] + s_red[3];
        s_red[10] = s_red[4] + s_red[5] + s_red[6] + s_red[7];
    }
    __syncthreads();
    const float ssum = s_red[9];

    dist[(size_t)b * K_ + tid] = ev / ssum;
    if (tid == 0)
        entropy[b] = logf(ssum) - s_red[10] / ssum;   // = -sum p log p
}

// ================== cooperative mega-kernel ====================================
// 512 blocks x 256 thr (2/CU). Phases separated by grid.sync():
//   P0 prep(all)  ->  P1 G1|conv  ->  P2 G2|conv  ->  P3 G3|conv  ->  P4 scores.
// Dataflow identical to the 5-launch r1/r7 pipeline; only launch boundaries and
// their tail-drains are removed.
#define C1V (65536 * 40)   // conv quads done in P1 (41%)
#define C2V (65536 * 75)   // by end of P2 (77%)
__global__ __launch_bounds__(256, 2) void mega_kernel(
    const float* __restrict__ E, const float* __restrict__ H,
    const float* __restrict__ Q, const float* __restrict__ W1,
    const float* __restrict__ b1, const float* __restrict__ W2,
    const float* __restrict__ b2, const float* __restrict__ emb_r,
    const float* __restrict__ emb_e, const float* __restrict__ mask,
    const int* __restrict__ r_space, const int* __restrict__ e_space,
    ushort* __restrict__ Xb, ushort* __restrict__ W1b,
    ushort* __restrict__ W2b, ushort* __restrict__ emb_rb,
    unsigned char* __restrict__ emb_e8, ushort* __restrict__ H1b,
    float* __restrict__ X2, ushort* __restrict__ X2rb, float* __restrict__ Rt,
    float* __restrict__ dist, float* __restrict__ entropy)
{
    cg::grid_group grid = cg::this_grid();
    __shared__ ushort Asl[2 * 64 * PITCH];   // 18 KB
    __shared__ ushort Bsl[2 * 64 * PITCH];   // 18 KB
    __shared__ int    s_e[K_];
    __shared__ float  s_x[16 * 20];
    __shared__ float  s_dot[K_];
    __shared__ float  s_red[12];

    const int bid = blockIdx.x;
    const int tid = threadIdx.x;

    // P0: prep (all 512 blocks, grid-stride)
    for (int t = bid * 256 + tid; t < PREPS_TOTAL; t += NBLK * 256)
        prep_one(t, E, H, Q, W1, W2, emb_r, Xb, W1b, W2b, emb_rb);
    grid.sync();

    // P1: G1 = relu(Xb @ W1b^T + b1) -> H1b   |   conv [0, C1V)
    if (bid < 256)
        gemm_tile<IN_, true, true, true, false>(Xb, W1b, b1, H1b, nullptr, nullptr,
                                                (bid & 7) * 64, (bid >> 3) * 64, Asl, Bsl);
    else
        conv_range(emb_e, emb_e8, 0, C1V, bid - 256);
    grid.sync();

    // P2: G2 = H1b @ W2b^T + b2 -> X2 (f32, n>=256) + X2rb (bf16, n<256) | conv
    if (bid < 256)
        gemm_tile<AD_, false, false, true, true>(H1b, W2b, b2, nullptr, X2, X2rb,
                                                 (bid & 7) * 64, (bid >> 3) * 64, Asl, Bsl);
    else
        conv_range(emb_e, emb_e8, C1V, C2V, bid - 256);
    grid.sync();

    // P3: G3 = X2rb @ emb_rb^T -> Rt (f32, stride 512)   |   conv tail
    if (bid < 256)
        gemm_tile<256, false, false, false, false>(X2rb, emb_rb, nullptr, nullptr, Rt, nullptr,
                                                   (bid & 7) * 64, (bid >> 3) * 64, Asl, Bsl);
    else
        conv_range(emb_e, emb_e8, C2V, EE_N4, bid - 256);
    grid.sync();

    // P4: scores — 4 batch rows per block
    #pragma unroll 1
    for (int rr = 0; rr < 4; ++rr) {
        __syncthreads();                         // protect s_* reuse across rows
        scores_row(bid + rr * NBLK, X2, Rt, emb_e8, mask, r_space, e_space,
                   dist, entropy, s_e, s_x, s_dot, s_red);
    }
}

extern "C" void kernel_launch(void* const* d_in, const int* in_sizes, int n_in,
                              void* d_out, int out_size, void* d_ws, size_t ws_size,
                              hipStream_t stream) {
    const float* E     = (const float*)d_in[0];
    const float* H     = (const float*)d_in[1];
    const float* Q     = (const float*)d_in[2];
    const float* W1    = (const float*)d_in[3];
    const float* b1    = (const float*)d_in[4];
    const float* W2    = (const float*)d_in[5];
    const float* b2    = (const float*)d_in[6];
    const float* emb_r = (const float*)d_in[7];
    const float* emb_e = (const float*)d_in[8];
    const float* mask  = (const float*)d_in[9];
    const int* r_space = (const int*)d_in[10];
    const int* e_space = (const int*)d_in[11];

    float* out_dist = (float*)d_out;
    float* out_ent  = out_dist + (size_t)B_ * K_;

    char* ws = (char*)d_ws;
    ushort* Xb     = (ushort*)ws;         ws += (size_t)B_ * IN_ * 2;    //  3.00 MB
    ushort* W1b    = (ushort*)ws;         ws += (size_t)AD_ * IN_ * 2;   //  0.75 MB
    ushort* W2b    = (ushort*)ws;         ws += (size_t)AD_ * AD_ * 2;   //  0.50 MB
    ushort* emb_rb = (ushort*)ws;         ws += (size_t)NRP_ * 256 * 2;  //  0.25 MB (rows 500-511 poison, unread)
    unsigned char* emb_e8 = (unsigned char*)ws; ws += (size_t)NE_ * 256; // 25.60 MB
    ushort* H1b    = (ushort*)ws;         ws += (size_t)B_ * AD_ * 2;    //  2.00 MB
    float*  X2     = (float*)ws;          ws += (size_t)B_ * AD_ * 4;    //  4.00 MB (n<256 left poisoned, unread)
    ushort* X2rb   = (ushort*)ws;         ws += (size_t)B_ * 256 * 2;    //  1.00 MB
    float*  Rt     = (float*)ws;          ws += (size_t)B_ * NRP_ * 4;   //  4.00 MB

    void* args[] = {
        (void*)&E, (void*)&H, (void*)&Q, (void*)&W1, (void*)&b1, (void*)&W2,
        (void*)&b2, (void*)&emb_r, (void*)&emb_e, (void*)&mask,
        (void*)&r_space, (void*)&e_space,
        (void*)&Xb, (void*)&W1b, (void*)&W2b, (void*)&emb_rb, (void*)&emb_e8,
        (void*)&H1b, (void*)&X2, (void*)&X2rb, (void*)&Rt,
        (void*)&out_dist, (void*)&out_ent
    };
    hipLaunchCooperativeKernel((void*)mega_kernel, dim3(NBLK), dim3(256),
                               args, 0, stream);
}

// Round 9
// 209.174 us; speedup vs baseline: 2.3403x; 2.3403x over previous
//
#include <hip/hip_runtime.h>
#include <hip/hip_bf16.h>
#include <hip/hip_fp8.h>
#include <math.h>

#define B_   2048
#define K_   256
#define AD_  512
#define IN_  768
#define NR_  500
#define NRP_ 512   // padded
#define NE_  100000

typedef __attribute__((ext_vector_type(8))) short short8;
typedef __attribute__((ext_vector_type(4))) float float4v;
typedef __attribute__((ext_vector_type(4))) float f32x4;

__device__ __forceinline__ unsigned short f2bf(float f) {
    unsigned int u = __float_as_uint(f);
    unsigned int r = u + 0x7FFF + ((u >> 16) & 1);   // round-to-nearest-even
    return (unsigned short)(r >> 16);
}
__device__ __forceinline__ unsigned char f2fp8(float f) {
    __hip_fp8_e4m3 t(f);                             // OCP e4m3, HW cvt on gfx950
    return (unsigned char)t.__x;
}
__device__ __forceinline__ float fp8tof(unsigned int byte) {
    __hip_fp8_e4m3 t; t.__x = (__hip_fp8_storage_t)byte; return (float)t;
}

// ---------------- prep_small: cast concat [E|H|Q] -> Xb, W1/W2/emb_r -> bf16 ----
#define X_N4  (B_ * IN_ / 4)     // 393,216
#define W1_N4 (AD_ * IN_ / 4)    // 98,304
#define W2_N4 (AD_ * AD_ / 4)    // 65,536
#define ER_N4 (NR_ * 256 / 4)    // 32,000
#define PREPS_TOTAL (X_N4 + W1_N4 + W2_N4 + ER_N4)
__global__ __launch_bounds__(256) void prep_small_kernel(
    const float* __restrict__ E, const float* __restrict__ H,
    const float* __restrict__ Q, const float* __restrict__ W1,
    const float* __restrict__ W2, const float* __restrict__ emb_r,
    ushort* __restrict__ Xb, ushort* __restrict__ W1b,
    ushort* __restrict__ W2b, ushort* __restrict__ emb_rb)
{
    int t = blockIdx.x * 256 + threadIdx.x;
    const float* src; ushort* dst; long off;
    if (t < X_N4) {
        const int base = t * 4;
        const int row = base / IN_, col = base % IN_;
        src = (col < 256) ? &E[row * 256 + col]
            : (col < 512) ? &H[row * 256 + col - 256]
                          : &Q[row * 256 + col - 512];
        const float4 v = *(const float4*)src;
        ushort4 o;
        o.x = f2bf(v.x); o.y = f2bf(v.y); o.z = f2bf(v.z); o.w = f2bf(v.w);
        *(ushort4*)&Xb[base] = o;
        return;
    }
    t -= X_N4;
    if (t < W1_N4)                 { src = W1;    dst = W1b;    off = t; }
    else if (t < W1_N4 + W2_N4)    { src = W2;    dst = W2b;    off = t - W1_N4; }
    else if (t < W1_N4 + W2_N4 + ER_N4) { src = emb_r; dst = emb_rb; off = t - W1_N4 - W2_N4; }
    else return;
    const float4 v = *(const float4*)&src[off * 4];
    ushort4 o;
    o.x = f2bf(v.x); o.y = f2bf(v.y); o.z = f2bf(v.z); o.w = f2bf(v.w);
    *(ushort4*)&dst[off * 4] = o;
}

// ---------------- emb_e -> fp8 conversion slab (run by spare GEMM blocks) ------
// r1-exact: 256 conversion blocks per GEMM kernel; 4-deep pipelined, NT reads.
#define EE_N4 (NE_ * 256 / 4)    // 6,400,000
__device__ __forceinline__ void conv_range(
    const float* __restrict__ emb_e, unsigned char* __restrict__ emb_e8,
    int q0, int q1, int cb)
{
    const int stride = 256 * 256;                 // 65,536 conversion threads
    const f32x4* __restrict__ src = (const f32x4*)emb_e;
    uchar4* __restrict__ dst = (uchar4*)emb_e8;
    int i = q0 + cb * 256 + (int)threadIdx.x;
    for (; i + 3 * stride < q1; i += 4 * stride) {
        f32x4 v0 = __builtin_nontemporal_load(src + i);
        f32x4 v1 = __builtin_nontemporal_load(src + i + stride);
        f32x4 v2 = __builtin_nontemporal_load(src + i + 2 * stride);
        f32x4 v3 = __builtin_nontemporal_load(src + i + 3 * stride);
        uchar4 o0, o1, o2, o3;
        o0.x = f2fp8(v0[0]); o0.y = f2fp8(v0[1]); o0.z = f2fp8(v0[2]); o0.w = f2fp8(v0[3]);
        o1.x = f2fp8(v1[0]); o1.y = f2fp8(v1[1]); o1.z = f2fp8(v1[2]); o1.w = f2fp8(v1[3]);
        o2.x = f2fp8(v2[0]); o2.y = f2fp8(v2[1]); o2.z = f2fp8(v2[2]); o2.w = f2fp8(v2[3]);
        o3.x = f2fp8(v3[0]); o3.y = f2fp8(v3[1]); o3.z = f2fp8(v3[2]); o3.w = f2fp8(v3[3]);
        dst[i] = o0; dst[i + stride] = o1; dst[i + 2 * stride] = o2; dst[i + 3 * stride] = o3;
    }
    for (; i < q1; i += stride) {
        f32x4 v = __builtin_nontemporal_load(src + i);
        uchar4 o;
        o.x = f2fp8(v[0]); o.y = f2fp8(v[1]); o.z = f2fp8(v[2]); o.w = f2fp8(v[3]);
        dst[i] = o;
    }
}

// ---------------- bf16 MFMA GEMM, BK=64, double-buffered LDS (r1-exact) --------
template<int K, bool RELU, bool OUT_BF16, bool BIAS, bool EMIT_RHALF>
__global__ __launch_bounds__(256) void gemm_bf16_kernel(
    const ushort* __restrict__ A, const ushort* __restrict__ Bw,
    const float* __restrict__ bias, ushort* __restrict__ outb,
    float* __restrict__ outf, ushort* __restrict__ rhalf,
    const float* __restrict__ emb_e, unsigned char* __restrict__ emb_e8,
    int q0, int q1)
{
    constexpr int PITCH = 72;                     // 64 + 8 pad (ushort units)
    __shared__ ushort Asl[2][64 * PITCH];
    __shared__ ushort Bsl[2][64 * PITCH];

    if (blockIdx.x >= 8) {                        // conversion block
        conv_range(emb_e, emb_e8, q0, q1, (int)(blockIdx.x - 8) * 32 + (int)blockIdx.y);
        return;
    }

    const int tid = threadIdx.x;
    const int lane = tid & 63, w = tid >> 6;
    const int n0 = blockIdx.x * 64, m0 = blockIdx.y * 64;
    const int lrow = tid >> 2, lcg = (tid & 3) * 16;  // 4 loaders/row x 32B
    const int q = lane >> 4, l16 = lane & 15;

    const ushort* aptr = &A[(size_t)(m0 + lrow) * K + lcg];
    const ushort* bptr = &Bw[(size_t)(n0 + lrow) * K + lcg];

    short8 ra0 = *(const short8*)aptr;
    short8 ra1 = *(const short8*)(aptr + 8);
    short8 rb0 = *(const short8*)bptr;
    short8 rb1 = *(const short8*)(bptr + 8);
    *(short8*)&Asl[0][lrow * PITCH + lcg]     = ra0;
    *(short8*)&Asl[0][lrow * PITCH + lcg + 8] = ra1;
    *(short8*)&Bsl[0][lrow * PITCH + lcg]     = rb0;
    *(short8*)&Bsl[0][lrow * PITCH + lcg + 8] = rb1;

    float4v acc[4] = {};
    int buf = 0;
    __syncthreads();
    for (int k0 = 0; k0 < K; k0 += 64) {
        if (k0 + 64 < K) {                        // prefetch next tile into regs
            ra0 = *(const short8*)(aptr + k0 + 64);
            ra1 = *(const short8*)(aptr + k0 + 64 + 8);
            rb0 = *(const short8*)(bptr + k0 + 64);
            rb1 = *(const short8*)(bptr + k0 + 64 + 8);
        }
        #pragma unroll
        for (int kh = 0; kh < 64; kh += 32) {
            const short8 af = *(const short8*)&Asl[buf][(w * 16 + l16) * PITCH + kh + q * 8];
            #pragma unroll
            for (int jn = 0; jn < 4; ++jn) {
                const short8 bfr = *(const short8*)&Bsl[buf][(jn * 16 + l16) * PITCH + kh + q * 8];
                acc[jn] = __builtin_amdgcn_mfma_f32_16x16x32_bf16(af, bfr, acc[jn], 0, 0, 0);
            }
        }
        if (k0 + 64 < K) {
            *(short8*)&Asl[buf ^ 1][lrow * PITCH + lcg]     = ra0;
            *(short8*)&Asl[buf ^ 1][lrow * PITCH + lcg + 8] = ra1;
            *(short8*)&Bsl[buf ^ 1][lrow * PITCH + lcg]     = rb0;
            *(short8*)&Bsl[buf ^ 1][lrow * PITCH + lcg + 8] = rb1;
            __syncthreads();
            buf ^= 1;
        }
    }
    #pragma unroll
    for (int jn = 0; jn < 4; ++jn) {
        const int n = n0 + jn * 16 + l16;
        const float bn = BIAS ? bias[n] : 0.0f;
        #pragma unroll
        for (int r = 0; r < 4; ++r) {
            const int m = m0 + w * 16 + q * 4 + r;
            float c = acc[jn][r] + bn;
            if (RELU) c = fmaxf(c, 0.0f);
            if (OUT_BF16) outb[(size_t)m * AD_ + n] = f2bf(c);
            else if (!EMIT_RHALF || n >= 256) outf[(size_t)m * AD_ + n] = c;
            if (EMIT_RHALF && n < 256) rhalf[(size_t)m * 256 + n] = f2bf(c);
        }
    }
}

// ---------------- scores + masked softmax + entropy (r7-exact) -----------------
// __launch_bounds__(256,8): 8 blocks/CU (32 waves/CU) for the gather phase;
// x[16] staged in padded LDS (stride 20 floats, uniform 2-way = free);
// bias/r_space/R loads deferred past the gather-dot phase.
__global__ __launch_bounds__(256, 8) void scores_kernel(
    const float* __restrict__ X2, const float* __restrict__ R,
    const unsigned char* __restrict__ emb_e8, const float* __restrict__ mask,
    const int* __restrict__ r_space, const int* __restrict__ e_space,
    float* __restrict__ dist, float* __restrict__ entropy)
{
    const int b = blockIdx.x;
    const int tid = threadIdx.x;
    const int lane = tid & 63, wid = tid >> 6;
    const int l16 = lane & 15, q4 = lane >> 4;   // row-span lane, row-quarter

    __shared__ int   s_e[K_];
    __shared__ float s_x[16 * 20];               // chunk c at [c*20], 16 floats
    __shared__ float s_dot[K_];
    __shared__ float s_red[12];

    {
        const int   e_mine = e_space[b * K_ + tid];
        const float mk     = mask[b * K_ + tid];
        s_e[tid] = (mk != 0.0f) ? e_mine : 0;    // dead gathers -> row 0 (L1-hot)
        s_x[(tid >> 4) * 20 + (tid & 15)] = X2[(size_t)b * AD_ + 256 + tid];
    }
    __syncthreads();

    // gather-dot: wave wid handles k in [wid*64, +64); 8 loads (32 rows) in flight
    const int kbase = wid * 64;
    #pragma unroll
    for (int it = 0; it < 2; ++it) {
        uint4 wv[8];
        #pragma unroll
        for (int u = 0; u < 8; ++u) {
            const int row = kbase + it * 32 + u * 4 + q4;
            wv[u] = *(const uint4*)&emb_e8[(size_t)s_e[row] * 256 + l16 * 16];
        }
        float p[8];
        #pragma unroll
        for (int u = 0; u < 8; ++u) {
            float a = 0.0f;
            #pragma unroll
            for (int w4 = 0; w4 < 4; ++w4) {
                const unsigned int d = (w4 == 0) ? wv[u].x : (w4 == 1) ? wv[u].y
                                     : (w4 == 2) ? wv[u].z : wv[u].w;
                const float4 xv = *(const float4*)&s_x[l16 * 20 + w4 * 4];
                a += fp8tof(d & 0xffu)         * xv.x + fp8tof((d >> 8) & 0xffu)  * xv.y
                   + fp8tof((d >> 16) & 0xffu) * xv.z + fp8tof(d >> 24)           * xv.w;
            }
            p[u] = a;
        }
        #pragma unroll
        for (int off = 8; off >= 1; off >>= 1) {
            #pragma unroll
            for (int u = 0; u < 8; ++u) p[u] += __shfl_down(p[u], off, 16);
        }
        if (l16 == 0) {
            #pragma unroll
            for (int u = 0; u < 8; ++u) s_dot[kbase + it * 32 + u * 4 + q4] = p[u];
        }
    }
    __syncthreads();

    // late bias: re-reads are L1/L2-hot
    const float mk2    = mask[b * K_ + tid];
    const int   r_mine = r_space[b * K_ + tid];
    const float bias   = R[(size_t)b * NRP_ + r_mine] - (1.0f - mk2) * 1e31f;
    const float v = s_dot[tid] + bias;

    // block max
    float m = v;
    #pragma unroll
    for (int off = 32; off >= 1; off >>= 1) m = fmaxf(m, __shfl_down(m, off));
    if (lane == 0) s_red[wid] = m;
    __syncthreads();
    if (tid == 0)
        s_red[8] = fmaxf(fmaxf(s_red[0], s_red[1]), fmaxf(s_red[2], s_red[3]));
    __syncthreads();
    const float bmax = s_red[8];

    // joint block sum of ev and ev*(v-bmax)
    const float ev = __expf(v - bmax);       // masked: exp(-1e31)=0
    float s = ev;
    float t = ev * (v - bmax);               // masked: 0 * finite = 0
    #pragma unroll
    for (int off = 32; off >= 1; off >>= 1) {
        s += __shfl_down(s, off);
        t += __shfl_down(t, off);
    }
    if (lane == 0) { s_red[wid] = s; s_red[4 + wid] = t; }
    __syncthreads();
    if (tid == 0) {
        s_red[9]  = s_red[0] + s_red[1] + s_red[2] + s_red[3];
        s_red[10] = s_red[4] + s_red[5] + s_red[6] + s_red[7];
    }
    __syncthreads();
    const float ssum = s_red[9];

    dist[(size_t)b * K_ + tid] = ev / ssum;
    if (tid == 0)
        entropy[b] = logf(ssum) - s_red[10] / ssum;   // = -sum p log p
}

extern "C" void kernel_launch(void* const* d_in, const int* in_sizes, int n_in,
                              void* d_out, int out_size, void* d_ws, size_t ws_size,
                              hipStream_t stream) {
    const float* E     = (const float*)d_in[0];
    const float* H     = (const float*)d_in[1];
    const float* Q     = (const float*)d_in[2];
    const float* W1    = (const float*)d_in[3];
    const float* b1    = (const float*)d_in[4];
    const float* W2    = (const float*)d_in[5];
    const float* b2    = (const float*)d_in[6];
    const float* emb_r = (const float*)d_in[7];
    const float* emb_e = (const float*)d_in[8];
    const float* mask  = (const float*)d_in[9];
    const int* r_space = (const int*)d_in[10];
    const int* e_space = (const int*)d_in[11];

    float* out_dist = (float*)d_out;
    float* out_ent  = out_dist + (size_t)B_ * K_;

    char* ws = (char*)d_ws;
    ushort* Xb     = (ushort*)ws;         ws += (size_t)B_ * IN_ * 2;    //  3.00 MB
    ushort* W1b    = (ushort*)ws;         ws += (size_t)AD_ * IN_ * 2;   //  0.75 MB
    ushort* W2b    = (ushort*)ws;         ws += (size_t)AD_ * AD_ * 2;   //  0.50 MB
    ushort* emb_rb = (ushort*)ws;         ws += (size_t)NRP_ * 256 * 2;  //  0.25 MB (rows 500-511 poison, unread)
    unsigned char* emb_e8 = (unsigned char*)ws; ws += (size_t)NE_ * 256; // 25.60 MB
    ushort* H1b    = (ushort*)ws;         ws += (size_t)B_ * AD_ * 2;    //  2.00 MB
    float*  X2     = (float*)ws;          ws += (size_t)B_ * AD_ * 4;    //  4.00 MB (n<256 left poisoned, unread)
    ushort* X2rb   = (ushort*)ws;         ws += (size_t)B_ * 256 * 2;    //  1.00 MB
    float*  Rt     = (float*)ws;          ws += (size_t)B_ * NRP_ * 4;   //  4.00 MB

    // emb_e -> fp8 quad ranges per GEMM kernel (multiples of 65,536 = conv threads)
    const int Q1 = 65536 * 40;            // 2,621,440  (41% -> GEMM1, K=768)
    const int Q2 = 65536 * 70;            // 4,587,520  (next 31% -> GEMM2)

    prep_small_kernel<<<(PREPS_TOTAL + 255) / 256, 256, 0, stream>>>(
        E, H, Q, W1, W2, emb_r, Xb, W1b, W2b, emb_rb);

    dim3 g(16, 32);   // x<8: GEMM tiles (8,32); x>=8: 256 conversion blocks
    gemm_bf16_kernel<IN_, true,  true,  true,  false><<<g, 256, 0, stream>>>(
        Xb, W1b, b1, H1b, nullptr, nullptr, emb_e, emb_e8, 0, Q1);
    gemm_bf16_kernel<AD_, false, false, true,  true ><<<g, 256, 0, stream>>>(
        H1b, W2b, b2, nullptr, X2, X2rb, emb_e, emb_e8, Q1, Q2);
    // R = X2[:, :256] @ emb_r^T  -> [B, 512pad] f32
    gemm_bf16_kernel<256, false, false, false, false><<<g, 256, 0, stream>>>(
        X2rb, emb_rb, nullptr, nullptr, Rt, nullptr, emb_e, emb_e8, Q2, EE_N4);

    scores_kernel<<<B_, 256, 0, stream>>>(X2, Rt, emb_e8, mask,
                                          r_space, e_space, out_dist, out_ent);
}